// Round 9
// baseline (139.831 us; speedup 1.0000x reference)
//
#include <hip/hip_runtime.h>

typedef unsigned short u16;
typedef unsigned char u8;
typedef __attribute__((ext_vector_type(8))) short bf16x8;   // 8 bf16 = 4 VGPR
typedef __attribute__((ext_vector_type(4))) float f32x4;
typedef __attribute__((ext_vector_type(8))) unsigned short u16x8;

#define DEVI static __device__ __forceinline__

constexpr int Bb = 8, Nn = 2048, Dd = 256;

DEVI u16 f2bf(float f) {
    unsigned int u = __builtin_bit_cast(unsigned int, f);
    u = (u + 0x7fffu + ((u >> 16) & 1u)) >> 16;   // RNE
    return (u16)u;
}
DEVI float bf2f(u16 v) {
    return __builtin_bit_cast(float, (unsigned int)v << 16);
}

// float -> fp8 e4m3fn (OCP), RNE, handles subnormals; our data |x| < 1
DEVI unsigned f2e4m3(float f) {
    unsigned u = __builtin_bit_cast(unsigned, f);
    unsigned s = (u >> 24) & 0x80u;
    int e = (int)((u >> 23) & 0xffu) - 127;
    unsigned m = u & 0x7fffffu;
    if (e >= -6) {
        if (e >= 8) return s | 0x7eu;          // clamp (not expected)
        unsigned m3 = m >> 20;
        unsigned rest = m & 0xfffffu;
        m3 += (rest > 0x80000u) || ((rest == 0x80000u) && (m3 & 1u));
        return s | (((unsigned)(e + 7) << 3) + m3);
    }
    if (e >= -9) {                              // subnormal, quantum 2^-9
        unsigned full = 0x800000u | m;
        int shift = 23 - (e + 9);               // 21..23
        unsigned qv = full >> shift;
        unsigned rest = full & ((1u << shift) - 1u);
        unsigned half = 1u << (shift - 1);
        qv += (rest > half) || ((rest == half) && (qv & 1u));
        return s | qv;                          // qv==8 encodes 2^-6 correctly
    }
    if (e == -10 && m != 0) return s | 1u;
    return s;
}

// async global->LDS, 16B per lane; lds dest = wave-uniform base (+lane*16 by HW)
DEVI void gl_lds16(const void* g, void* l) {
    __builtin_amdgcn_global_load_lds(
        (const __attribute__((address_space(1))) unsigned int*)g,
        (__attribute__((address_space(3))) unsigned int*)l, 16, 0, 0);
}

// ---------------- prep: x -> bf16 xb + fp8 x8 + transposed xbt + row ss -----
__global__ __launch_bounds__(256) void prep_xt_kernel(
    const float* __restrict__ x, u16* __restrict__ xb, u16* __restrict__ xbt,
    u8* __restrict__ x8, float* __restrict__ sq) {
    int n0 = blockIdx.x * 64;
    int b = blockIdx.y;
    int t = threadIdx.x;
    __shared__ __align__(16) u16 tile[64 * 256];   // row stride 512B, swizzled
    int row = t >> 2;
    int c0 = (t & 3) * 64;
    size_t gr = (size_t)(b * Nn + n0 + row);
    const float* xr = x + gr * Dd + c0;
    u16* xbr = xb + gr * Dd + c0;
    float ss = 0.f;
    unsigned wpk[16];
#pragma unroll
    for (int cc = 0; cc < 16; ++cc) {
        float4 v = *(const float4*)(xr + cc * 4);
        ss += v.x * v.x + v.y * v.y + v.z * v.z + v.w * v.w;
        ushort4 o;
        o.x = f2bf(v.x); o.y = f2bf(v.y); o.z = f2bf(v.z); o.w = f2bf(v.w);
        *(ushort4*)(xbr + cc * 4) = o;
        int cb = (c0 + cc * 4) * 2;
        *(ushort4*)((char*)tile + row * 512 + (cb ^ ((row & 7) << 4))) = o;
        wpk[cc] = f2e4m3(v.x) | (f2e4m3(v.y) << 8) | (f2e4m3(v.z) << 16) | (f2e4m3(v.w) << 24);
    }
#pragma unroll
    for (int k = 0; k < 4; ++k) {
        uint4 pw;
        pw.x = wpk[k * 4]; pw.y = wpk[k * 4 + 1]; pw.z = wpk[k * 4 + 2]; pw.w = wpk[k * 4 + 3];
        *(uint4*)(x8 + gr * 256 + c0 + k * 16) = pw;
    }
    ss += __shfl_xor(ss, 1);
    ss += __shfl_xor(ss, 2);
    if ((t & 3) == 0) sq[gr] = ss;
    __syncthreads();
#pragma unroll
    for (int p = 0; p < 8; ++p) {
        int d = p * 32 + (t >> 3);
        int n8 = (t & 7) * 8;
        u16x8 vv;
#pragma unroll
        for (int e = 0; e < 8; ++e) {
            int r2 = n8 + e;
            vv[e] = *(const u16*)((char*)tile + r2 * 512 + ((d * 2) ^ ((r2 & 7) << 4)));
        }
        *(u16x8*)(xbt + ((size_t)(b * Dd + d)) * Nn + n0 + n8) = vv;
    }
}

// ---------------- prep: W -> bf16 ------------------------------------------
__global__ void prep_w_kernel(const float* __restrict__ W, u16* __restrict__ Wb) {
    int i = (blockIdx.x * 256 + threadIdx.x) * 4;
    const float4 v = *(const float4*)(W + i);
    ushort4 o;
    o.x = f2bf(v.x); o.y = f2bf(v.y); o.z = f2bf(v.z); o.w = f2bf(v.w);
    *(ushort4*)(Wb + i) = o;
}

// ---------------- fused: S^T = Xm.Xn^T (fp8), P = mean_h exp(-dist/denom),
//                  O += P.Xm (bf16).  512 thr = 8 waves x 32 n-rows.
// 6-phase tile schedule: small read bursts + barrier + lgkm0 + setprio'd MFMA
// clusters; staging issued at phase 1, drained at phase 6.
// LDS carve (133120 B): sqT 2K | xm8A 16K | xm8B 16K | xmtA 32K | xmtB 32K | sP 32K
__global__ __launch_bounds__(512, 2) void fused_adj_kernel(
    const u8* __restrict__ x8, const u16* __restrict__ xbt,
    const float* __restrict__ sq, const float* __restrict__ lsig,
    u16* __restrict__ opart) {
    int bid = blockIdx.x;
    int xcd = bid & 7, j = bid >> 3;
    int g = xcd + 8 * (j >> 3);      // 4 (b,q) pairs per XCD
    int nt8 = j & 7;
    int b = g >> 2, q = g & 3;
    int r0 = b * Nn + nt8 * 256;     // first n-row (global)
    int m0b = b * Nn + q * 512;      // first m-row of quarter (global)
    int mq0 = q * 512;               // first m-col of quarter (within batch)

    int tid = threadIdx.x;
    int w = tid >> 6, l = tid & 63;
    int l15 = l & 15, lhi = l >> 4;
    int swz = (l15 & 7) << 4;

    __shared__ __align__(16) char smem[133120];
    float* sqT = (float*)smem;                    // 2 KiB (512 floats)
    char* _xm8A = smem + 2048;                    // 16K [64m][256B fp8] swizzled
    char* _xm8B = smem + 2048 + 16384;
    char* _xmtA = smem + 2048 + 32768;            // 32K [256d][128B bf16] swizzled
    char* _xmtB = smem + 2048 + 65536;
    char* _sPw = smem + 2048 + 98304 + w * 4096;  // per-wave P [32n][128B] swizzled

    float nc[4];
#pragma unroll
    for (int h = 0; h < 4; ++h) {
        float denom = 2.f * expf(2.f * lsig[h]) + 1e-6f;
        nc[h] = -1.44269504f / denom;
    }
    bool uniform = (lsig[0] == lsig[1]) && (lsig[1] == lsig[2]) && (lsig[2] == lsig[3]);

    sqT[tid] = sq[m0b + tid];

    // Xn fp8 fragments: wave owns n rows [w*32, w*32+32)
    long bf8[2][8];
    float sqn[2];
#pragma unroll
    for (int rg = 0; rg < 2; ++rg) {
        const u8* xr = x8 + (size_t)(r0 + w * 32 + rg * 16 + l15) * 256;
#pragma unroll
        for (int kt = 0; kt < 8; ++kt) bf8[rg][kt] = *(const long*)(xr + kt * 32 + lhi * 8);
        sqn[rg] = sq[r0 + w * 32 + rg * 16 + l15];
    }

    f32x4 of[2][16];
#pragma unroll
    for (int rg = 0; rg < 2; ++rg)
#pragma unroll
        for (int dt = 0; dt < 16; ++dt) of[rg][dt] = (f32x4){0.f, 0.f, 0.f, 0.f};

#define STAGE(XM8, XMT, tt) {                                                  \
    _Pragma("unroll") for (int it = 0; it < 2; ++it) {                         \
        int c = w * 2 + it;                                                    \
        int row = c * 4 + (l >> 4);                                            \
        gl_lds16(x8 + (size_t)(m0b + (tt) * 64 + row) * 256 +                  \
                     (((l & 15) * 16) ^ ((row & 7) << 4)),                     \
                 (XM8) + c * 1024);                                            \
    }                                                                           \
    _Pragma("unroll") for (int it = 0; it < 4; ++it) {                         \
        int c = w * 4 + it;                                                    \
        int drow = c * 8 + (l >> 3);                                           \
        gl_lds16(xbt + (size_t)(b * Dd + drow) * Nn + mq0 + (tt) * 64 +        \
                     (((l & 7) ^ (drow & 7)) * 8),                             \
                 (XMT) + c * 1024);                                            \
    } }

// exp + pack + per-wave P write for one m-subtile (16 m)
#define PWRITE(mt, SA, SB, SMV) {                                              \
    float sm_[4] = {(SMV).x, (SMV).y, (SMV).z, (SMV).w};                       \
    _Pragma("unroll") for (int rg = 0; rg < 2; ++rg) {                         \
        f32x4 sfv = rg ? (SB) : (SA);                                          \
        ushort4 pk;                                                            \
        _Pragma("unroll") for (int r = 0; r < 4; ++r) {                        \
            float d2 = fmaxf(fmaf(-2.f, sfv[r], sqn[rg] + sm_[r]), 0.f);       \
            float p = exp2f(d2 * nc[0]);                                       \
            if (!uniform)                                                      \
                p = 0.25f * (p + exp2f(d2 * nc[1]) + exp2f(d2 * nc[2]) +       \
                             exp2f(d2 * nc[3]));                               \
            ((u16*)&pk)[r] = f2bf(p);                                          \
        }                                                                       \
        int n_ = rg * 16 + l15;                                                \
        *(ushort4*)(_sPw + n_ * 128 + (((mt) * 32 + lhi * 8) ^ ((n_ & 7) << 4))) = pk; \
    } }

// S-phase MFMA cluster for two m-subtiles
#define SCL(AV0, AV1, S0A, S0B, S1A, S1B) {                                    \
    __builtin_amdgcn_s_setprio(1);                                             \
    _Pragma("unroll") for (int kt = 0; kt < 8; ++kt) {                         \
        S0A = __builtin_amdgcn_mfma_f32_16x16x32_fp8_fp8(AV0[kt], bf8[0][kt], S0A, 0, 0, 0); \
        S0B = __builtin_amdgcn_mfma_f32_16x16x32_fp8_fp8(AV0[kt], bf8[1][kt], S0B, 0, 0, 0); \
        S1A = __builtin_amdgcn_mfma_f32_16x16x32_fp8_fp8(AV1[kt], bf8[0][kt], S1A, 0, 0, 0); \
        S1B = __builtin_amdgcn_mfma_f32_16x16x32_fp8_fp8(AV1[kt], bf8[1][kt], S1B, 0, 0, 0); \
    }                                                                           \
    __builtin_amdgcn_s_setprio(0); }

#define BAR_LGKM  __builtin_amdgcn_s_barrier();                                \
                  asm volatile("s_waitcnt lgkmcnt(0)" ::: "memory");

#define ITER(CXM8, CXMT, NXM8, NXMT, t, SN) {                                  \
    f32x4 s0a = {0,0,0,0}, s0b = {0,0,0,0}, s1a = {0,0,0,0}, s1b = {0,0,0,0};  \
    f32x4 s2a = {0,0,0,0}, s2b = {0,0,0,0}, s3a = {0,0,0,0}, s3b = {0,0,0,0};  \
    float4 smv0, smv1, smv2, smv3;                                             \
    /* ---- Phase 1: stage(next) + A(mt0,1) + sq(mt0,1); S MFMA mt0,1 ---- */  \
    if (SN) STAGE(NXM8, NXMT, (t) + 1)                                         \
    {                                                                           \
        long av0[8], av1[8];                                                   \
        _Pragma("unroll") for (int kt = 0; kt < 8; ++kt) {                     \
            av0[kt] = *(const long*)((CXM8) + l15 * 256 + ((kt * 32 + lhi * 8) ^ swz)); \
            av1[kt] = *(const long*)((CXM8) + (16 + l15) * 256 + ((kt * 32 + lhi * 8) ^ swz)); \
        }                                                                       \
        smv0 = *(const float4*)(sqT + (t) * 64 + lhi * 4);                     \
        smv1 = *(const float4*)(sqT + (t) * 64 + 16 + lhi * 4);                \
        BAR_LGKM                                                               \
        SCL(av0, av1, s0a, s0b, s1a, s1b)                                      \
        __builtin_amdgcn_s_barrier();                                          \
    }                                                                           \
    /* ---- Phase 2: A(mt2,3) + sq + P-write(mt0,1); S MFMA mt2,3 ---- */      \
    {                                                                           \
        long av2[8], av3[8];                                                   \
        _Pragma("unroll") for (int kt = 0; kt < 8; ++kt) {                     \
            av2[kt] = *(const long*)((CXM8) + (32 + l15) * 256 + ((kt * 32 + lhi * 8) ^ swz)); \
            av3[kt] = *(const long*)((CXM8) + (48 + l15) * 256 + ((kt * 32 + lhi * 8) ^ swz)); \
        }                                                                       \
        smv2 = *(const float4*)(sqT + (t) * 64 + 32 + lhi * 4);                \
        smv3 = *(const float4*)(sqT + (t) * 64 + 48 + lhi * 4);                \
        PWRITE(0, s0a, s0b, smv0)                                              \
        PWRITE(1, s1a, s1b, smv1)                                              \
        BAR_LGKM                                                               \
        SCL(av2, av3, s2a, s2b, s3a, s3b)                                      \
        __builtin_amdgcn_s_barrier();                                          \
    }                                                                           \
    /* ---- Phases 3-6: PV, 16 MFMA per phase ---- */                          \
    bf16x8 pa0, pa1;                                                           \
    {   /* Phase 3: P-write(mt2,3) + pa(kt2=0) + bv dt0-7 */                   \
        PWRITE(2, s2a, s2b, smv2)                                              \
        PWRITE(3, s3a, s3b, smv3)                                              \
        pa0 = *(const bf16x8*)(_sPw + l15 * 128 + ((lhi * 16) ^ swz));         \
        pa1 = *(const bf16x8*)(_sPw + (16 + l15) * 128 + ((lhi * 16) ^ swz));  \
        bf16x8 bv[8];                                                          \
        _Pragma("unroll") for (int dt = 0; dt < 8; ++dt)                       \
            bv[dt] = *(const bf16x8*)((CXMT) + (dt * 16 + l15) * 128 + ((lhi * 16) ^ swz)); \
        BAR_LGKM                                                               \
        __builtin_amdgcn_s_setprio(1);                                         \
        _Pragma("unroll") for (int dt = 0; dt < 8; ++dt) {                     \
            of[0][dt] = __builtin_amdgcn_mfma_f32_16x16x32_bf16(pa0, bv[dt], of[0][dt], 0, 0, 0); \
            of[1][dt] = __builtin_amdgcn_mfma_f32_16x16x32_bf16(pa1, bv[dt], of[1][dt], 0, 0, 0); \
        }                                                                       \
        __builtin_amdgcn_s_setprio(0);                                         \
        __builtin_amdgcn_s_barrier();                                          \
    }                                                                           \
    {   /* Phase 4: bv dt8-15 (kt2=0) */                                       \
        bf16x8 bv[8];                                                          \
        _Pragma("unroll") for (int dt = 0; dt < 8; ++dt)                       \
            bv[dt] = *(const bf16x8*)((CXMT) + ((dt + 8) * 16 + l15) * 128 + ((lhi * 16) ^ swz)); \
        BAR_LGKM                                                               \
        __builtin_amdgcn_s_setprio(1);                                         \
        _Pragma("unroll") for (int dt = 0; dt < 8; ++dt) {                     \
            of[0][dt + 8] = __builtin_amdgcn_mfma_f32_16x16x32_bf16(pa0, bv[dt], of[0][dt + 8], 0, 0, 0); \
            of[1][dt + 8] = __builtin_amdgcn_mfma_f32_16x16x32_bf16(pa1, bv[dt], of[1][dt + 8], 0, 0, 0); \
        }                                                                       \
        __builtin_amdgcn_s_setprio(0);                                         \
        __builtin_amdgcn_s_barrier();                                          \
    }                                                                           \
    {   /* Phase 5: pa(kt2=1) + bv dt0-7 */                                    \
        pa0 = *(const bf16x8*)(_sPw + l15 * 128 + ((64 + lhi * 16) ^ swz));    \
        pa1 = *(const bf16x8*)(_sPw + (16 + l15) * 128 + ((64 + lhi * 16) ^ swz)); \
        bf16x8 bv[8];                                                          \
        _Pragma("unroll") for (int dt = 0; dt < 8; ++dt)                       \
            bv[dt] = *(const bf16x8*)((CXMT) + (dt * 16 + l15) * 128 + ((64 + lhi * 16) ^ swz)); \
        BAR_LGKM                                                               \
        __builtin_amdgcn_s_setprio(1);                                         \
        _Pragma("unroll") for (int dt = 0; dt < 8; ++dt) {                     \
            of[0][dt] = __builtin_amdgcn_mfma_f32_16x16x32_bf16(pa0, bv[dt], of[0][dt], 0, 0, 0); \
            of[1][dt] = __builtin_amdgcn_mfma_f32_16x16x32_bf16(pa1, bv[dt], of[1][dt], 0, 0, 0); \
        }                                                                       \
        __builtin_amdgcn_s_setprio(0);                                         \
        __builtin_amdgcn_s_barrier();                                          \
    }                                                                           \
    {   /* Phase 6: bv dt8-15 (kt2=1); drain staging; tile boundary */         \
        bf16x8 bv[8];                                                          \
        _Pragma("unroll") for (int dt = 0; dt < 8; ++dt)                       \
            bv[dt] = *(const bf16x8*)((CXMT) + ((dt + 8) * 16 + l15) * 128 + ((64 + lhi * 16) ^ swz)); \
        BAR_LGKM                                                               \
        __builtin_amdgcn_s_setprio(1);                                         \
        _Pragma("unroll") for (int dt = 0; dt < 8; ++dt) {                     \
            of[0][dt + 8] = __builtin_amdgcn_mfma_f32_16x16x32_bf16(pa0, bv[dt], of[0][dt + 8], 0, 0, 0); \
            of[1][dt + 8] = __builtin_amdgcn_mfma_f32_16x16x32_bf16(pa1, bv[dt], of[1][dt + 8], 0, 0, 0); \
        }                                                                       \
        __builtin_amdgcn_s_setprio(0);                                         \
        asm volatile("s_waitcnt vmcnt(0)" ::: "memory");                       \
        __builtin_amdgcn_s_barrier();                                          \
    } }

    STAGE(_xm8A, _xmtA, 0)
    __syncthreads();

    for (int tt = 0; tt < 4; ++tt) {
        ITER(_xm8A, _xmtA, _xm8B, _xmtB, tt * 2, true)
        ITER(_xm8B, _xmtB, _xm8A, _xmtA, tt * 2 + 1, (tt < 3))
    }

#undef STAGE
#undef PWRITE
#undef SCL
#undef BAR_LGKM
#undef ITER

    // write bf16 partial for this m-quarter
    u16* od = opart + (size_t)q * ((size_t)Bb * Nn * Dd);
#pragma unroll
    for (int rg = 0; rg < 2; ++rg)
#pragma unroll
        for (int dt = 0; dt < 16; ++dt)
#pragma unroll
            for (int r = 0; r < 4; ++r) {
                size_t row = (size_t)(r0 + w * 32 + rg * 16 + lhi * 4 + r);
                od[row * Dd + dt * 16 + l15] = f2bf(of[rg][dt][r]);
            }
}

// ---------------- projection (sum(partials) @ W^T + b) + ELU + residual + LN
__global__ __launch_bounds__(512, 1) void proj_ln_kernel(
    const u16* __restrict__ opart, const u16* __restrict__ Wb,
    const u16* __restrict__ xbres, const float* __restrict__ bvec,
    const float* __restrict__ gamma, const float* __restrict__ beta,
    float* __restrict__ out) {
    int tid = threadIdx.x, w = tid >> 6, l = tid & 63;
    int rg = w & 3, h = w >> 2;
    int lrow = l & 15, lhi = l >> 4;
    size_t row0 = (size_t)blockIdx.x * 64 + rg * 16;
    const size_t QS = (size_t)Bb * Nn * Dd;

    __shared__ __align__(16) float xch[8 * 16 * 2 * 64];   // 64 KiB

    f32x4 acc[16];
#pragma unroll
    for (int jt = 0; jt < 16; ++jt) acc[jt] = (f32x4){0.f, 0.f, 0.f, 0.f};

#pragma unroll
    for (int kk = 0; kk < 4; ++kk) {
        int kc = h * 4 + kk;
        float as[8] = {0.f, 0.f, 0.f, 0.f, 0.f, 0.f, 0.f, 0.f};
#pragma unroll
        for (int qq = 0; qq < 4; ++qq) {
            u16x8 v = *(const u16x8*)(opart + QS * qq + (row0 + lrow) * Dd + kc * 32 + lhi * 8);
#pragma unroll
            for (int e = 0; e < 8; ++e) as[e] += bf2f(v[e]);
        }
        bf16x8 a;
#pragma unroll
        for (int e = 0; e < 8; ++e) a[e] = (short)f2bf(as[e]);
#pragma unroll
        for (int jt = 0; jt < 16; ++jt) {
            bf16x8 bv = *(const bf16x8*)(Wb + (size_t)(jt * 16 + lrow) * Dd + kc * 32 + lhi * 8);
            acc[jt] = __builtin_amdgcn_mfma_f32_16x16x32_bf16(a, bv, acc[jt], 0, 0, 0);
        }
    }

    // exchange: write my OTHER-half r values; partner (w^4) wrote my half
#pragma unroll
    for (int jt = 0; jt < 16; ++jt)
#pragma unroll
        for (int qq = 0; qq < 2; ++qq) {
            int r = (1 - h) * 2 + qq;
            xch[(w * 16 + jt) * 128 + qq * 64 + l] = acc[jt][r];
        }
    __syncthreads();
#pragma unroll
    for (int jt = 0; jt < 16; ++jt)
#pragma unroll
        for (int qq = 0; qq < 2; ++qq)
            acc[jt][h * 2 + qq] += xch[((w ^ 4) * 16 + jt) * 128 + qq * 64 + l];

#pragma unroll
    for (int qq = 0; qq < 2; ++qq) {
        int r = h * 2 + qq;
        size_t grow = row0 + lhi * 4 + r;
        float vbuf[16];
        float s1 = 0.f, s2 = 0.f;
#pragma unroll
        for (int jt = 0; jt < 16; ++jt) {
            int jcol = jt * 16 + lrow;
            float v = acc[jt][r] + bvec[jcol];
            float e = v > 0.f ? v : (exp2f(v * 1.44269504f) - 1.f);   // ELU
            float res = e + bf2f(xbres[grow * Dd + jcol]);
            vbuf[jt] = res;
            s1 += res;
            s2 += res * res;
        }
#pragma unroll
        for (int m = 1; m < 16; m <<= 1) {
            s1 += __shfl_xor(s1, m);
            s2 += __shfl_xor(s2, m);
        }
        float mean = s1 * (1.f / 256.f);
        float var = s2 * (1.f / 256.f) - mean * mean;
        float rstd = rsqrtf(var + 1e-5f);
#pragma unroll
        for (int jt = 0; jt < 16; ++jt) {
            int jcol = jt * 16 + lrow;
            out[grow * Dd + jcol] = (vbuf[jt] - mean) * rstd * gamma[jcol] + beta[jcol];
        }
    }
}

// ---------------------------------------------------------------------------
extern "C" void kernel_launch(void* const* d_in, const int* in_sizes, int n_in,
                              void* d_out, int out_size, void* d_ws, size_t ws_size,
                              hipStream_t stream) {
    const float* x = (const float*)d_in[0];
    const float* lsig = (const float*)d_in[1];
    const float* W = (const float*)d_in[2];
    const float* bvec = (const float*)d_in[3];
    const float* gamma = (const float*)d_in[4];
    const float* beta = (const float*)d_in[5];
    float* out = (float*)d_out;

    char* ws = (char*)d_ws;
    u16* xb = (u16*)ws;                                   // 8 MiB
    u16* xbt = (u16*)(ws + 8388608);                      // 8 MiB
    float* sq = (float*)(ws + 16777216);                  // 64 KiB
    u16* Wb = (u16*)(ws + 16842752);                      // 128 KiB
    u8* x8 = (u8*)(ws + 16973824);                        // 4 MiB fp8
    u16* opart = (u16*)(ws + 21168128);                   // 4 x 8 MiB bf16 partials

    prep_xt_kernel<<<dim3(Nn / 64, Bb), dim3(256), 0, stream>>>(x, xb, xbt, x8, sq);
    prep_w_kernel<<<dim3(64), dim3(256), 0, stream>>>(W, Wb);
    fused_adj_kernel<<<dim3(256), dim3(512), 0, stream>>>(x8, xbt, sq, lsig, opart);
    proj_ln_kernel<<<dim3(Bb * Nn / 64), dim3(512), 0, stream>>>(opart, Wb, xb, bvec, gamma, beta, out);
}

// Round 11
// 104.157 us; speedup vs baseline: 1.3425x; 1.3425x over previous
//
#include <hip/hip_runtime.h>

typedef unsigned short u16;
typedef unsigned char u8;
typedef __attribute__((ext_vector_type(8))) short bf16x8;   // 8 bf16 = 4 VGPR
typedef __attribute__((ext_vector_type(4))) float f32x4;
typedef __attribute__((ext_vector_type(8))) unsigned short u16x8;

#define DEVI static __device__ __forceinline__

constexpr int Bb = 8, Nn = 2048, Dd = 256;

DEVI u16 f2bf(float f) {
    unsigned int u = __builtin_bit_cast(unsigned int, f);
    u = (u + 0x7fffu + ((u >> 16) & 1u)) >> 16;   // RNE
    return (u16)u;
}
DEVI float bf2f(u16 v) {
    return __builtin_bit_cast(float, (unsigned int)v << 16);
}

// float -> fp8 e4m3fn (OCP), RNE, handles subnormals; our data |x| < 1
DEVI unsigned f2e4m3(float f) {
    unsigned u = __builtin_bit_cast(unsigned, f);
    unsigned s = (u >> 24) & 0x80u;
    int e = (int)((u >> 23) & 0xffu) - 127;
    unsigned m = u & 0x7fffffu;
    if (e >= -6) {
        if (e >= 8) return s | 0x7eu;          // clamp (not expected)
        unsigned m3 = m >> 20;
        unsigned rest = m & 0xfffffu;
        m3 += (rest > 0x80000u) || ((rest == 0x80000u) && (m3 & 1u));
        return s | (((unsigned)(e + 7) << 3) + m3);
    }
    if (e >= -9) {                              // subnormal, quantum 2^-9
        unsigned full = 0x800000u | m;
        int shift = 23 - (e + 9);               // 21..23
        unsigned qv = full >> shift;
        unsigned rest = full & ((1u << shift) - 1u);
        unsigned half = 1u << (shift - 1);
        qv += (rest > half) || ((rest == half) && (qv & 1u));
        return s | qv;                          // qv==8 encodes 2^-6 correctly
    }
    if (e == -10 && m != 0) return s | 1u;
    return s;
}

// async global->LDS, 16B per lane; lds dest = wave-uniform base (+lane*16 by HW)
DEVI void gl_lds16(const void* g, void* l) {
    __builtin_amdgcn_global_load_lds(
        (const __attribute__((address_space(1))) unsigned int*)g,
        (__attribute__((address_space(3))) unsigned int*)l, 16, 0, 0);
}

// ---------------- prep: x -> bf16 xb + fp8 x8 + transposed xbt + row ss -----
__global__ __launch_bounds__(256) void prep_xt_kernel(
    const float* __restrict__ x, u16* __restrict__ xb, u16* __restrict__ xbt,
    u8* __restrict__ x8, float* __restrict__ sq) {
    int n0 = blockIdx.x * 64;
    int b = blockIdx.y;
    int t = threadIdx.x;
    __shared__ __align__(16) u16 tile[64 * 256];   // row stride 512B, swizzled
    int row = t >> 2;
    int c0 = (t & 3) * 64;
    size_t gr = (size_t)(b * Nn + n0 + row);
    const float* xr = x + gr * Dd + c0;
    u16* xbr = xb + gr * Dd + c0;
    float ss = 0.f;
    unsigned wpk[16];
#pragma unroll
    for (int cc = 0; cc < 16; ++cc) {
        float4 v = *(const float4*)(xr + cc * 4);
        ss += v.x * v.x + v.y * v.y + v.z * v.z + v.w * v.w;
        ushort4 o;
        o.x = f2bf(v.x); o.y = f2bf(v.y); o.z = f2bf(v.z); o.w = f2bf(v.w);
        *(ushort4*)(xbr + cc * 4) = o;
        int cb = (c0 + cc * 4) * 2;
        *(ushort4*)((char*)tile + row * 512 + (cb ^ ((row & 7) << 4))) = o;
        wpk[cc] = f2e4m3(v.x) | (f2e4m3(v.y) << 8) | (f2e4m3(v.z) << 16) | (f2e4m3(v.w) << 24);
    }
#pragma unroll
    for (int k = 0; k < 4; ++k) {
        uint4 pw;
        pw.x = wpk[k * 4]; pw.y = wpk[k * 4 + 1]; pw.z = wpk[k * 4 + 2]; pw.w = wpk[k * 4 + 3];
        *(uint4*)(x8 + gr * 256 + c0 + k * 16) = pw;
    }
    ss += __shfl_xor(ss, 1);
    ss += __shfl_xor(ss, 2);
    if ((t & 3) == 0) sq[gr] = ss;
    __syncthreads();
#pragma unroll
    for (int p = 0; p < 8; ++p) {
        int d = p * 32 + (t >> 3);
        int n8 = (t & 7) * 8;
        u16x8 vv;
#pragma unroll
        for (int e = 0; e < 8; ++e) {
            int r2 = n8 + e;
            vv[e] = *(const u16*)((char*)tile + r2 * 512 + ((d * 2) ^ ((r2 & 7) << 4)));
        }
        *(u16x8*)(xbt + ((size_t)(b * Dd + d)) * Nn + n0 + n8) = vv;
    }
}

// ---------------- prep: W -> bf16 ------------------------------------------
__global__ void prep_w_kernel(const float* __restrict__ W, u16* __restrict__ Wb) {
    int i = (blockIdx.x * 256 + threadIdx.x) * 4;
    const float4 v = *(const float4*)(W + i);
    ushort4 o;
    o.x = f2bf(v.x); o.y = f2bf(v.y); o.z = f2bf(v.z); o.w = f2bf(v.w);
    *(ushort4*)(Wb + i) = o;
}

// ---------------- fused: S^T = Xm.Xn^T (fp8), P = mean_h exp(-dist/denom),
//                  O += P.Xm (bf16).
// R3-champion structure VERBATIM (512 thr = 8 waves x 32 n-rows, single-
// buffered staging, __syncthreads pairs); single change: S operands are fp8
// (sXm 16K fp8, A-reads b64, frags from x8). Everything else untouched.
__global__ __launch_bounds__(512, 1) void fused_adj_kernel(
    const u8* __restrict__ x8, const u16* __restrict__ xbt,
    const float* __restrict__ sq, const float* __restrict__ lsig,
    u16* __restrict__ opart) {
    int bid = blockIdx.x;
    // XCD grouping: 8 blocks sharing (batch b, quarter q) land on one XCD
    int xcd = bid & 7, j = bid >> 3;
    int g = xcd + 8 * (j >> 3);      // 0..31
    int nt8 = j & 7;                 // n-tile within batch
    int b = g >> 2, q = g & 3;
    int r0 = b * Nn + nt8 * 256;     // first n-row (global)
    int m0b = b * Nn + q * 512;      // first m-row of quarter (global)
    int mq0 = q * 512;               // first m-col of quarter (within batch)

    int tid = threadIdx.x;
    int w = tid >> 6, l = tid & 63;
    int l15 = l & 15, lhi = l >> 4;

    // LDS 80KB: sXm8 64x256B fp8 (16K) | sXmt 256x128B bf16 (32K) | sP 8 x 4K
    __shared__ __align__(16) char smem[81920];
    char* sXm8 = smem;
    char* sXmt = smem + 16384;
    char* sP = smem + 49152 + w * 4096;

    float nc[4];
#pragma unroll
    for (int h = 0; h < 4; ++h) {
        float denom = 2.f * expf(2.f * lsig[h]) + 1e-6f;
        nc[h] = -1.44269504f / denom;
    }
    bool uniform = (lsig[0] == lsig[1]) && (lsig[1] == lsig[2]) && (lsig[2] == lsig[3]);

    // Xn fp8 fragments in registers: 2 row-groups x 8 k-tiles
    long bf8[2][8];
    float sqn[2];
#pragma unroll
    for (int rg = 0; rg < 2; ++rg) {
        const u8* xr = x8 + (size_t)(r0 + w * 32 + rg * 16 + l15) * 256;
#pragma unroll
        for (int kt = 0; kt < 8; ++kt) bf8[rg][kt] = *(const long*)(xr + kt * 32 + lhi * 8);
        sqn[rg] = sq[r0 + w * 32 + rg * 16 + l15];
    }

    f32x4 of[2][16];
#pragma unroll
    for (int rg = 0; rg < 2; ++rg)
#pragma unroll
        for (int dt = 0; dt < 16; ++dt) of[rg][dt] = (f32x4){0.f, 0.f, 0.f, 0.f};

    int swz = (l15 & 7) << 4;        // read-side XOR for 16-row strided reads

    for (int t = 0; t < 8; ++t) {
        int m0 = m0b + t * 64;
        __syncthreads();
        // stage Xm fp8 (64 x 256B): linear LDS + inverse-swizzled source
#pragma unroll
        for (int it = 0; it < 2; ++it) {
            int c = w * 2 + it;                  // chunk of 1024B = 4 rows
            int row = c * 4 + (l >> 4);
            gl_lds16(x8 + (size_t)(m0 + row) * 256 + (((l & 15) * 16) ^ ((row & 7) << 4)),
                     sXm8 + c * 1024);
        }
        // stage Xm^T bf16 (256 x 128B)
#pragma unroll
        for (int it = 0; it < 4; ++it) {
            int c0 = it * 512 + w * 64;
            int c = c0 + l;
            int row = c >> 3, c16 = c & 7;
            gl_lds16(xbt + (size_t)(b * Dd + row) * Nn + (mq0 + t * 64) + (c16 ^ (row & 7)) * 8,
                     sXmt + c0 * 16);
        }
        __syncthreads();

        // S^T phase: per m-subtile, 8 A-reads (b64) feed 16 fp8 MFMAs
#pragma unroll
        for (int mt = 0; mt < 4; ++mt) {
            float4 sqm = *(const float4*)(sq + m0 + mt * 16 + lhi * 4);
            f32x4 sfv0 = (f32x4){0.f, 0.f, 0.f, 0.f};
            f32x4 sfv1 = (f32x4){0.f, 0.f, 0.f, 0.f};
#pragma unroll
            for (int kt = 0; kt < 8; ++kt) {
                long av = *(const long*)(sXm8 + (mt * 16 + l15) * 256 +
                                         ((kt * 32 + lhi * 8) ^ swz));
                sfv0 = __builtin_amdgcn_mfma_f32_16x16x32_fp8_fp8(av, bf8[0][kt], sfv0, 0, 0, 0);
                sfv1 = __builtin_amdgcn_mfma_f32_16x16x32_fp8_fp8(av, bf8[1][kt], sfv1, 0, 0, 0);
            }
            float sm[4] = {sqm.x, sqm.y, sqm.z, sqm.w};
            // P: lane holds fixed n = rg*16+l15, m = mt*16 + lhi*4 + r -> packed b64 write
#pragma unroll
            for (int rg = 0; rg < 2; ++rg) {
                f32x4 sfv = rg ? sfv1 : sfv0;
                ushort4 pk;
#pragma unroll
                for (int r = 0; r < 4; ++r) {
                    float d2 = fmaxf(fmaf(-2.f, sfv[r], sqn[rg] + sm[r]), 0.f);
                    float p = exp2f(d2 * nc[0]);
                    if (!uniform)
                        p = 0.25f * (p + exp2f(d2 * nc[1]) + exp2f(d2 * nc[2]) + exp2f(d2 * nc[3]));
                    ((u16*)&pk)[r] = f2bf(p);
                }
                int n = rg * 16 + l15;
                *(ushort4*)(sP + n * 128 + ((mt * 32 + lhi * 8) ^ ((n & 7) << 4))) = pk;
            }
        }

        // PV phase: O += P . Xm   (same-wave RAW on sP)
#pragma unroll
        for (int kt2 = 0; kt2 < 2; ++kt2) {
            bf16x8 pa0 = *(const bf16x8*)(sP + l15 * 128 + ((kt2 * 64 + lhi * 16) ^ swz));
            bf16x8 pa1 = *(const bf16x8*)(sP + (16 + l15) * 128 + ((kt2 * 64 + lhi * 16) ^ swz));
#pragma unroll
            for (int dt = 0; dt < 16; ++dt) {
                bf16x8 bv = *(const bf16x8*)(sXmt + (dt * 16 + l15) * 128 +
                                             ((kt2 * 64 + lhi * 16) ^ swz));
                of[0][dt] = __builtin_amdgcn_mfma_f32_16x16x32_bf16(pa0, bv, of[0][dt], 0, 0, 0);
                of[1][dt] = __builtin_amdgcn_mfma_f32_16x16x32_bf16(pa1, bv, of[1][dt], 0, 0, 0);
            }
        }
    }

    // write bf16 partial for this m-quarter
    u16* od = opart + (size_t)q * ((size_t)Bb * Nn * Dd);
#pragma unroll
    for (int rg = 0; rg < 2; ++rg)
#pragma unroll
        for (int dt = 0; dt < 16; ++dt)
#pragma unroll
            for (int r = 0; r < 4; ++r) {
                size_t row = (size_t)(r0 + w * 32 + rg * 16 + lhi * 4 + r);
                od[row * Dd + dt * 16 + l15] = f2bf(of[rg][dt][r]);
            }
}

// ---------------- projection (sum(partials) @ W^T + b) + ELU + residual + LN
__global__ __launch_bounds__(512, 1) void proj_ln_kernel(
    const u16* __restrict__ opart, const u16* __restrict__ Wb,
    const u16* __restrict__ xbres, const float* __restrict__ bvec,
    const float* __restrict__ gamma, const float* __restrict__ beta,
    float* __restrict__ out) {
    int tid = threadIdx.x, w = tid >> 6, l = tid & 63;
    int rg = w & 3, h = w >> 2;
    int lrow = l & 15, lhi = l >> 4;
    size_t row0 = (size_t)blockIdx.x * 64 + rg * 16;
    const size_t QS = (size_t)Bb * Nn * Dd;

    __shared__ __align__(16) float xch[8 * 16 * 2 * 64];   // 64 KiB

    f32x4 acc[16];
#pragma unroll
    for (int jt = 0; jt < 16; ++jt) acc[jt] = (f32x4){0.f, 0.f, 0.f, 0.f};

#pragma unroll
    for (int kk = 0; kk < 4; ++kk) {
        int kc = h * 4 + kk;
        float as[8] = {0.f, 0.f, 0.f, 0.f, 0.f, 0.f, 0.f, 0.f};
#pragma unroll
        for (int qq = 0; qq < 4; ++qq) {
            u16x8 v = *(const u16x8*)(opart + QS * qq + (row0 + lrow) * Dd + kc * 32 + lhi * 8);
#pragma unroll
            for (int e = 0; e < 8; ++e) as[e] += bf2f(v[e]);
        }
        bf16x8 a;
#pragma unroll
        for (int e = 0; e < 8; ++e) a[e] = (short)f2bf(as[e]);
#pragma unroll
        for (int jt = 0; jt < 16; ++jt) {
            bf16x8 bv = *(const bf16x8*)(Wb + (size_t)(jt * 16 + lrow) * Dd + kc * 32 + lhi * 8);
            acc[jt] = __builtin_amdgcn_mfma_f32_16x16x32_bf16(a, bv, acc[jt], 0, 0, 0);
        }
    }

    // exchange: write my OTHER-half r values; partner (w^4) wrote my half
#pragma unroll
    for (int jt = 0; jt < 16; ++jt)
#pragma unroll
        for (int qq = 0; qq < 2; ++qq) {
            int r = (1 - h) * 2 + qq;
            xch[(w * 16 + jt) * 128 + qq * 64 + l] = acc[jt][r];
        }
    __syncthreads();
#pragma unroll
    for (int jt = 0; jt < 16; ++jt)
#pragma unroll
        for (int qq = 0; qq < 2; ++qq)
            acc[jt][h * 2 + qq] += xch[((w ^ 4) * 16 + jt) * 128 + qq * 64 + l];

#pragma unroll
    for (int qq = 0; qq < 2; ++qq) {
        int r = h * 2 + qq;
        size_t grow = row0 + lhi * 4 + r;
        float vbuf[16];
        float s1 = 0.f, s2 = 0.f;
#pragma unroll
        for (int jt = 0; jt < 16; ++jt) {
            int jcol = jt * 16 + lrow;
            float v = acc[jt][r] + bvec[jcol];
            float e = v > 0.f ? v : (exp2f(v * 1.44269504f) - 1.f);   // ELU
            float res = e + bf2f(xbres[grow * Dd + jcol]);
            vbuf[jt] = res;
            s1 += res;
            s2 += res * res;
        }
#pragma unroll
        for (int m = 1; m < 16; m <<= 1) {
            s1 += __shfl_xor(s1, m);
            s2 += __shfl_xor(s2, m);
        }
        float mean = s1 * (1.f / 256.f);
        float var = s2 * (1.f / 256.f) - mean * mean;
        float rstd = rsqrtf(var + 1e-5f);
#pragma unroll
        for (int jt = 0; jt < 16; ++jt) {
            int jcol = jt * 16 + lrow;
            out[grow * Dd + jcol] = (vbuf[jt] - mean) * rstd * gamma[jcol] + beta[jcol];
        }
    }
}

// ---------------------------------------------------------------------------
extern "C" void kernel_launch(void* const* d_in, const int* in_sizes, int n_in,
                              void* d_out, int out_size, void* d_ws, size_t ws_size,
                              hipStream_t stream) {
    const float* x = (const float*)d_in[0];
    const float* lsig = (const float*)d_in[1];
    const float* W = (const float*)d_in[2];
    const float* bvec = (const float*)d_in[3];
    const float* gamma = (const float*)d_in[4];
    const float* beta = (const float*)d_in[5];
    float* out = (float*)d_out;

    char* ws = (char*)d_ws;
    u16* xb = (u16*)ws;                                   // 8 MiB
    u16* xbt = (u16*)(ws + 8388608);                      // 8 MiB
    float* sq = (float*)(ws + 16777216);                  // 64 KiB
    u16* Wb = (u16*)(ws + 16842752);                      // 128 KiB
    u8* x8 = (u8*)(ws + 16973824);                        // 4 MiB fp8
    u16* opart = (u16*)(ws + 21168128);                   // 4 x 8 MiB bf16 partials

    prep_xt_kernel<<<dim3(Nn / 64, Bb), dim3(256), 0, stream>>>(x, xb, xbt, x8, sq);
    prep_w_kernel<<<dim3(64), dim3(256), 0, stream>>>(W, Wb);
    fused_adj_kernel<<<dim3(256), dim3(512), 0, stream>>>(x8, xbt, sq, lsig, opart);
    proj_ln_kernel<<<dim3(Bb * Nn / 64), dim3(512), 0, stream>>>(opart, Wb, xb, bvec, gamma, beta, out);
}